// Round 3
// baseline (321.097 us; speedup 1.0000x reference)
//
#include <hip/hip_runtime.h>
#include <hip/hip_bf16.h>

using bf16x8 = __bf16 __attribute__((ext_vector_type(8)));
using f32x4  = float  __attribute__((ext_vector_type(4)));
using u16x8  = unsigned short __attribute__((ext_vector_type(8)));
using u16x4  = unsigned short __attribute__((ext_vector_type(4)));

__device__ __forceinline__ unsigned short f2bf(float f) {
  unsigned u = __builtin_bit_cast(unsigned, f);
  u += 0x7fffu + ((u >> 16) & 1u);
  return (unsigned short)(u >> 16);
}
__device__ __forceinline__ float bf2f(unsigned short h) {
  return __builtin_bit_cast(float, (unsigned)h << 16);
}

__device__ __forceinline__ void gload16(const void* g, void* l) {
  __builtin_amdgcn_global_load_lds(
      (const __attribute__((address_space(1))) void*)g,
      (__attribute__((address_space(3))) void*)l, 16, 0, 0);
}

// ---------------- convert f32 -> bf16 (vectorized) ----------------
__global__ __launch_bounds__(256) void conv_f32_bf16(const float* __restrict__ in,
                                                     unsigned short* __restrict__ out, int n) {
  int stride = gridDim.x * 256 * 4;
  for (int i = (blockIdx.x * 256 + threadIdx.x) * 4; i < n; i += stride) {
    float4 v = *reinterpret_cast<const float4*>(in + i);
    u16x4 o = { f2bf(v.x), f2bf(v.y), f2bf(v.z), f2bf(v.w) };
    *reinterpret_cast<u16x4*>(out + i) = o;
  }
}

// ---------------- transpose + convert: out[c][r] = bf16(in[r][c]) ----------------
__global__ __launch_bounds__(256) void transpose_f32_bf16(const float* __restrict__ in,
                                                          unsigned short* __restrict__ out,
                                                          int R, int C) {
  __shared__ float t[64][65];
  int c0 = blockIdx.x * 64, r0 = blockIdx.y * 64;
  int lx = threadIdx.x & 63, ly = threadIdx.x >> 6;
#pragma unroll
  for (int i = 0; i < 16; ++i) {
    int r = ly * 16 + i;
    t[r][lx] = in[(size_t)(r0 + r) * C + c0 + lx];
  }
  __syncthreads();
#pragma unroll
  for (int i = 0; i < 16; ++i) {
    int c = ly * 16 + i;
    out[(size_t)(c0 + c) * R + r0 + lx] = f2bf(t[lx][c]);
  }
}

// ---------------- shared 128x128xK bf16 MFMA mainloop (BK=32, 4 waves) ----------------
__device__ __forceinline__ void gemm_mainloop(
    const unsigned short* __restrict__ A, const unsigned short* __restrict__ Bt,
    int lda, int ldb, int K, int brow, int bcol,
    unsigned short* As, unsigned short* Bs, f32x4 (&acc)[4][4]) {
  const int tid  = threadIdx.x;
  const int lane = tid & 63;
  const int w    = tid >> 6;
  const int wr   = (w >> 1) * 64, wc = (w & 1) * 64;
  const int lr   = lane & 15, kg = lane >> 4;

  // staging: tile is 128 rows x 32 cols bf16 (8KB); 256 thr * 16B = 4KB -> 2 rounds
  const int e    = tid * 8;
  const int srow = e >> 5, scol = e & 31;
  const unsigned short* ga0 = A  + (size_t)(brow + srow) * lda + scol;
  const unsigned short* ga1 = A  + (size_t)(brow + srow + 64) * lda + scol;
  const unsigned short* gb0 = Bt + (size_t)(bcol + srow) * ldb + scol;
  const unsigned short* gb1 = Bt + (size_t)(bcol + srow + 64) * ldb + scol;
  unsigned short* da0 = As + (tid & 192) * 8;           // wave-uniform LDS base
  unsigned short* da1 = As + 2048 + (tid & 192) * 8;
  unsigned short* db0 = Bs + (tid & 192) * 8;
  unsigned short* db1 = Bs + 2048 + (tid & 192) * 8;

  const unsigned short* pa = As + (wr + lr) * 32 + kg * 8;
  const unsigned short* pb = Bs + (wc + lr) * 32 + kg * 8;

  for (int k0 = 0; k0 < K; k0 += 32) {
    gload16(ga0, da0);
    gload16(ga1, da1);
    gload16(gb0, db0);
    gload16(gb1, db1);
    ga0 += 32; ga1 += 32; gb0 += 32; gb1 += 32;
    __syncthreads();
    bf16x8 af[4], bfr[4];
#pragma unroll
    for (int m = 0; m < 4; ++m)
      af[m] = __builtin_bit_cast(bf16x8, *reinterpret_cast<const u16x8*>(pa + m * 16 * 32));
#pragma unroll
    for (int n = 0; n < 4; ++n)
      bfr[n] = __builtin_bit_cast(bf16x8, *reinterpret_cast<const u16x8*>(pb + n * 16 * 32));
#pragma unroll
    for (int m = 0; m < 4; ++m)
#pragma unroll
      for (int n = 0; n < 4; ++n)
        acc[m][n] = __builtin_amdgcn_mfma_f32_16x16x32_bf16(af[m], bfr[n], acc[m][n], 0, 0, 0);
    __syncthreads();
  }
}

// ---------------- GEMM1: qkv = x @ W_qkv, epilogue: elu+1 on q,k; scatter to (B,H,N,D) ----------------
__global__ __launch_bounds__(256) void gemm_qkv(
    const unsigned short* __restrict__ xbf, const unsigned short* __restrict__ wt,
    unsigned short* __restrict__ q, unsigned short* __restrict__ k, unsigned short* __restrict__ v) {
  __shared__ unsigned short As[128 * 32];
  __shared__ unsigned short Bs[128 * 32];
  f32x4 acc[4][4] = {};
  const int brow = blockIdx.x * 128, bcol = blockIdx.y * 128;
  gemm_mainloop(xbf, wt, 1024, 1024, 1024, brow, bcol, As, Bs, acc);

  const int lane = threadIdx.x & 63, w = threadIdx.x >> 6;
  const int wr = (w >> 1) * 64, wc = (w & 1) * 64;
  const int lr = lane & 15, hi = lane >> 4;
#pragma unroll
  for (int m = 0; m < 4; ++m)
#pragma unroll
    for (int n = 0; n < 4; ++n)
#pragma unroll
      for (int r = 0; r < 4; ++r) {
        int grow = brow + wr + m * 16 + hi * 4 + r;
        int gcol = bcol + wc + n * 16 + lr;
        float val = acc[m][n][r];
        int t = gcol >> 10;
        int h = (gcol >> 6) & 15;
        int d = gcol & 63;
        int b = grow >> 12, s = grow & 4095;
        size_t idx = ((size_t)(b * 16 + h) * 4096 + s) * 64 + d;
        if (t < 2) {
          val = val > 0.f ? val + 1.f : __expf(val);  // elu(x)+1
          (t == 0 ? q : k)[idx] = f2bf(val);
        } else {
          v[idx] = f2bf(val);
        }
      }
}

// ---------------- GEMM2: out = attn @ W_out + b ----------------
__global__ __launch_bounds__(256) void gemm_out(
    const unsigned short* __restrict__ attn, const unsigned short* __restrict__ wt,
    const float* __restrict__ bias, float* __restrict__ out) {
  __shared__ unsigned short As[128 * 32];
  __shared__ unsigned short Bs[128 * 32];
  f32x4 acc[4][4] = {};
  const int brow = blockIdx.x * 128, bcol = blockIdx.y * 128;
  gemm_mainloop(attn, wt, 1024, 1024, 1024, brow, bcol, As, Bs, acc);

  const int lane = threadIdx.x & 63, w = threadIdx.x >> 6;
  const int wr = (w >> 1) * 64, wc = (w & 1) * 64;
  const int lr = lane & 15, hi = lane >> 4;
#pragma unroll
  for (int m = 0; m < 4; ++m)
#pragma unroll
    for (int n = 0; n < 4; ++n)
#pragma unroll
      for (int r = 0; r < 4; ++r) {
        int grow = brow + wr + m * 16 + hi * 4 + r;
        int gcol = bcol + wc + n * 16 + lr;
        out[(size_t)grow * 1024 + gcol] = acc[m][n][r] + bias[gcol];
      }
}

// ---------------- kv[d][e] = sum_n k[n][d] v[n][e]  (stored transposed [e][d]); ksum[d] ----------------
__global__ __launch_bounds__(256) void kv_kernel(
    const unsigned short* __restrict__ k, const unsigned short* __restrict__ v,
    float* __restrict__ kv, float* __restrict__ ksum) {
  const int bid = blockIdx.x;             // B*H*8 = 512
  const int bh = bid >> 3, chunk = bid & 7;
  const unsigned short* kb = k + (size_t)bh * 4096 * 64 + chunk * 512 * 64;
  const unsigned short* vb = v + (size_t)bh * 4096 * 64 + chunk * 512 * 64;
  __shared__ unsigned short ks[64 * 64];
  __shared__ unsigned short vs[64 * 64];
  const int tid = threadIdx.x;
  const int ty = tid >> 4, tx = tid & 15;   // d-group, e-group
  float acc[4][4] = {};
  float ksacc[4] = {};
  for (int t = 0; t < 8; ++t) {
    const unsigned short* ksrc = kb + t * 4096;
    const unsigned short* vsrc = vb + t * 4096;
    *reinterpret_cast<u16x8*>(&ks[tid * 8])        = *reinterpret_cast<const u16x8*>(ksrc + tid * 8);
    *reinterpret_cast<u16x8*>(&ks[2048 + tid * 8]) = *reinterpret_cast<const u16x8*>(ksrc + 2048 + tid * 8);
    *reinterpret_cast<u16x8*>(&vs[tid * 8])        = *reinterpret_cast<const u16x8*>(vsrc + tid * 8);
    *reinterpret_cast<u16x8*>(&vs[2048 + tid * 8]) = *reinterpret_cast<const u16x8*>(vsrc + 2048 + tid * 8);
    __syncthreads();
#pragma unroll 4
    for (int nn = 0; nn < 64; ++nn) {
      u16x4 ku = *reinterpret_cast<const u16x4*>(&ks[nn * 64 + ty * 4]);
      u16x4 vu = *reinterpret_cast<const u16x4*>(&vs[nn * 64 + tx * 4]);
      float kd[4], ve[4];
#pragma unroll
      for (int i = 0; i < 4; ++i) { kd[i] = bf2f(ku[i]); ve[i] = bf2f(vu[i]); }
#pragma unroll
      for (int i = 0; i < 4; ++i) ksacc[i] += kd[i];
#pragma unroll
      for (int i = 0; i < 4; ++i)
#pragma unroll
        for (int j = 0; j < 4; ++j) acc[i][j] += kd[i] * ve[j];
    }
    __syncthreads();
  }
  float* kvb = kv + (size_t)bh * 4096;
#pragma unroll
  for (int i = 0; i < 4; ++i)
#pragma unroll
    for (int j = 0; j < 4; ++j)
      atomicAdd(&kvb[(tx * 4 + j) * 64 + ty * 4 + i], acc[i][j]);  // [e][d]
  if (tx == 0) {
#pragma unroll
    for (int i = 0; i < 4; ++i) atomicAdd(&ksum[bh * 64 + ty * 4 + i], ksacc[i]);
  }
}

// ---------------- num = q @ kv ; out_attn = num / (q.ksum + 1e-6), to (B,N,C) bf16 ----------------
__global__ __launch_bounds__(256) void num_kernel(
    const unsigned short* __restrict__ q, const float* __restrict__ kv,
    const float* __restrict__ ksum, unsigned short* __restrict__ attn) {
  const int bid = blockIdx.x;              // B*H*64 = 4096
  const int bh = bid >> 6, sblk = bid & 63;
  const int b = bh >> 4, h = bh & 15;
  __shared__ unsigned short kvs[64 * 72];  // [e][d], padded stride 72
  __shared__ float ksum_s[64];
  __shared__ float norm_s[64];
  const int tid = threadIdx.x;
  const float* kvb = kv + (size_t)bh * 4096;
#pragma unroll
  for (int r = 0; r < 4; ++r) {
    int e = r * 1024 + tid * 4;
    float4 f = *reinterpret_cast<const float4*>(&kvb[e]);
    int row = e >> 6, col = e & 63;
    u16x4 o = { f2bf(f.x), f2bf(f.y), f2bf(f.z), f2bf(f.w) };
    *reinterpret_cast<u16x4*>(&kvs[row * 72 + col]) = o;
  }
  if (tid < 16) {
    float4 f = *reinterpret_cast<const float4*>(&ksum[bh * 64 + tid * 4]);
    ksum_s[tid * 4 + 0] = f.x; ksum_s[tid * 4 + 1] = f.y;
    ksum_s[tid * 4 + 2] = f.z; ksum_s[tid * 4 + 3] = f.w;
  }
  __syncthreads();

  const int lane = tid & 63, w = tid >> 6;
  const int lr = lane & 15, kg = lane >> 4;
  const int s0 = sblk * 64 + w * 16;
  const unsigned short* qrow = q + ((size_t)bh * 4096 + s0 + lr) * 64 + kg * 8;
  u16x8 a0u = *reinterpret_cast<const u16x8*>(qrow);
  u16x8 a1u = *reinterpret_cast<const u16x8*>(qrow + 32);
  bf16x8 a0 = __builtin_bit_cast(bf16x8, a0u);
  bf16x8 a1 = __builtin_bit_cast(bf16x8, a1u);

  // normalizer for row (s0+lr): partial over this lane's d-slice, reduce across kg
  float p = 0.f;
#pragma unroll
  for (int j = 0; j < 8; ++j) {
    p += bf2f(a0u[j]) * ksum_s[kg * 8 + j];
    p += bf2f(a1u[j]) * ksum_s[32 + kg * 8 + j];
  }
  p += __shfl_xor(p, 16);
  p += __shfl_xor(p, 32);
  if (kg == 0) norm_s[w * 16 + lr] = p;

  f32x4 accs[4];
#pragma unroll
  for (int jf = 0; jf < 4; ++jf) {
    u16x8 b0u = *reinterpret_cast<const u16x8*>(&kvs[(jf * 16 + lr) * 72 + kg * 8]);
    u16x8 b1u = *reinterpret_cast<const u16x8*>(&kvs[(jf * 16 + lr) * 72 + 32 + kg * 8]);
    f32x4 c = {0.f, 0.f, 0.f, 0.f};
    c = __builtin_amdgcn_mfma_f32_16x16x32_bf16(a0, __builtin_bit_cast(bf16x8, b0u), c, 0, 0, 0);
    c = __builtin_amdgcn_mfma_f32_16x16x32_bf16(a1, __builtin_bit_cast(bf16x8, b1u), c, 0, 0, 0);
    accs[jf] = c;
  }
  float dn[4];
#pragma unroll
  for (int r = 0; r < 4; ++r) dn[r] = norm_s[w * 16 + kg * 4 + r] + 1e-6f;

  unsigned short* ab = attn + (size_t)b * 4096 * 1024 + h * 64;
#pragma unroll
  for (int jf = 0; jf < 4; ++jf)
#pragma unroll
    for (int r = 0; r < 4; ++r) {
      int s = s0 + kg * 4 + r;
      int e2 = jf * 16 + lr;
      ab[(size_t)s * 1024 + e2] = f2bf(accs[jf][r] / dn[r]);
    }
}

extern "C" void kernel_launch(void* const* d_in, const int* in_sizes, int n_in,
                              void* d_out, int out_size, void* d_ws, size_t ws_size,
                              hipStream_t stream) {
  const float* x     = (const float*)d_in[0];
  const float* W_qkv = (const float*)d_in[1];
  const float* W_out = (const float*)d_in[2];
  const float* b_out = (const float*)d_in[3];
  float* out = (float*)d_out;

  // workspace layout (attn aliases xbf; xbf dead after gemm_qkv)
  unsigned short* xbf   = (unsigned short*)d_ws;            // 16384*1024
  unsigned short* attnb = xbf;                               // alias
  unsigned short* wqkvT = xbf + 16777216;                    // 3072*1024
  unsigned short* woutT = wqkvT + 3145728;                   // 1024*1024
  unsigned short* qb    = woutT + 1048576;                   // 16777216
  unsigned short* kb    = qb + 16777216;
  unsigned short* vb    = kb + 16777216;
  float* kvw            = (float*)(vb + 16777216);           // 262144 f32
  float* ksumw          = kvw + 262144;                      // 4096 f32

  conv_f32_bf16<<<2048, 256, 0, stream>>>(x, xbf, 16777216);
  transpose_f32_bf16<<<dim3(48, 16), 256, 0, stream>>>(W_qkv, wqkvT, 1024, 3072);
  transpose_f32_bf16<<<dim3(16, 16), 256, 0, stream>>>(W_out, woutT, 1024, 1024);
  hipMemsetAsync(kvw, 0, (262144 + 4096) * sizeof(float), stream);
  gemm_qkv<<<dim3(128, 24), 256, 0, stream>>>(xbf, wqkvT, qb, kb, vb);
  kv_kernel<<<512, 256, 0, stream>>>(kb, vb, kvw, ksumw);
  num_kernel<<<4096, 256, 0, stream>>>(qb, kvw, ksumw, attnb);
  gemm_out<<<dim3(128, 8), 256, 0, stream>>>(attnb, woutT, b_out, out);
}

// Round 4
// 268.759 us; speedup vs baseline: 1.1947x; 1.1947x over previous
//
#include <hip/hip_runtime.h>
#include <hip/hip_bf16.h>

using bf16x8 = __bf16 __attribute__((ext_vector_type(8)));
using f32x4  = float  __attribute__((ext_vector_type(4)));
using u16x8  = unsigned short __attribute__((ext_vector_type(8)));
using u16x4  = unsigned short __attribute__((ext_vector_type(4)));

__device__ __forceinline__ unsigned short f2bf(float f) {
  unsigned u = __builtin_bit_cast(unsigned, f);
  u += 0x7fffu + ((u >> 16) & 1u);
  return (unsigned short)(u >> 16);
}
__device__ __forceinline__ float bf2f(unsigned short h) {
  return __builtin_bit_cast(float, (unsigned)h << 16);
}

__device__ __forceinline__ void gload16(const void* g, void* l) {
  __builtin_amdgcn_global_load_lds(
      (const __attribute__((address_space(1))) void*)g,
      (__attribute__((address_space(3))) void*)l, 16, 0, 0);
}

__device__ __forceinline__ void barrier_raw() {
  asm volatile("" ::: "memory");
  __builtin_amdgcn_s_barrier();
  asm volatile("" ::: "memory");
}
#define LGKM0() asm volatile("s_waitcnt lgkmcnt(0)" ::: "memory")
#define VMC6()  asm volatile("s_waitcnt vmcnt(6)" ::: "memory")
#define VMC0()  asm volatile("s_waitcnt vmcnt(0)" ::: "memory")

// ---------------- convert f32 -> bf16 (vectorized) ----------------
__global__ __launch_bounds__(256) void conv_f32_bf16(const float* __restrict__ in,
                                                     unsigned short* __restrict__ out, int n) {
  int stride = gridDim.x * 256 * 4;
  for (int i = (blockIdx.x * 256 + threadIdx.x) * 4; i < n; i += stride) {
    float4 v = *reinterpret_cast<const float4*>(in + i);
    u16x4 o = { f2bf(v.x), f2bf(v.y), f2bf(v.z), f2bf(v.w) };
    *reinterpret_cast<u16x4*>(out + i) = o;
  }
}

// ---------------- transpose + convert: out[c][r] = bf16(in[r][c]) ----------------
__global__ __launch_bounds__(256) void transpose_f32_bf16(const float* __restrict__ in,
                                                          unsigned short* __restrict__ out,
                                                          int R, int C) {
  __shared__ float t[64][65];
  int c0 = blockIdx.x * 64, r0 = blockIdx.y * 64;
  int lx = threadIdx.x & 63, ly = threadIdx.x >> 6;
#pragma unroll
  for (int i = 0; i < 16; ++i) {
    int r = ly * 16 + i;
    t[r][lx] = in[(size_t)(r0 + r) * C + c0 + lx];
  }
  __syncthreads();
#pragma unroll
  for (int i = 0; i < 16; ++i) {
    int c = ly * 16 + i;
    out[(size_t)(c0 + c) * R + r0 + lx] = f2bf(t[lx][c]);
  }
}

// ================= 256x256, BK=64, 8-wave, 8-phase GEMM mainloop =================
// LDS per buffer (64KB): A [2 halves][128][64]bf16 at +0, B same at +32768.
// Double buffer -> 128KB. Reads XOR-swizzled (byte ^= (row&7)<<4); stages use
// linear LDS dest + inverse-swizzled global source (involution).
__device__ __forceinline__ void gemm256_mainloop(
    const unsigned short* __restrict__ A, const unsigned short* __restrict__ Bt,
    int brow, int bcol, char* lds, f32x4 (&acc)[8][4]) {
  constexpr int NT = 16;  // K = 1024 / 64
  const int tid  = threadIdx.x;
  const int lane = tid & 63;
  const int w    = tid >> 6;
  const int wr   = w >> 2, wc = w & 3;
  const int lr   = lane & 15, kg = lane >> 4;

  // stage source byte offsets (pre-swizzled): LDS linear byte o holds global
  // logical byte o ^ ((row&7)<<4) of the 128x64 half-tile (ld = 1024 elems)
  const int o0 = tid * 16;
  const int o1 = 8192 + tid * 16;
  const int p0 = o0 ^ (((o0 >> 7) & 7) << 4);
  const int p1 = o1 ^ (((o1 >> 7) & 7) << 4);
  const int off0 = (p0 >> 7) * 2048 + (p0 & 127);
  const int off1 = (p1 >> 7) * 2048 + (p1 & 127);
  const int wq = w << 10;  // wave-uniform LDS slice

  // swizzled read column offsets
  const int xr  = (lr & 7) << 4;
  const int ck0 = (kg * 16) ^ xr;
  const int ck1 = (64 + kg * 16) ^ xr;
  const int aoff = wr * 16384 + lr * 128;                              // A half = wr
  const int boff = 32768 + (wc >> 1) * 16384 + (wc & 1) * 8192 + lr * 128;  // B half = wc>>1

  auto STAGE = [&](const unsigned short* G, int rowbase, int t, int region) {
    const char* gb = (const char*)(G + (size_t)rowbase * 1024 + t * 64);
    char* lb = lds + region + wq;
    gload16(gb + off0, lb);
    gload16(gb + off1, lb + 8192);
  };

  // ---- prologue: tile0 full + 3 half-tiles of tile1 ----
  STAGE(Bt, bcol,       0, 32768);
  STAGE(Bt, bcol + 128, 0, 32768 + 16384);
  STAGE(A,  brow,       0, 0);
  STAGE(A,  brow + 128, 0, 16384);
  STAGE(Bt, bcol,       1, 65536 + 32768);
  STAGE(Bt, bcol + 128, 1, 65536 + 32768 + 16384);
  STAGE(A,  brow,       1, 65536);
  VMC6();         // tile0's 4 half-tiles landed; 3 of tile1 in flight
  barrier_raw();

  bf16x8 aF[4][2], bF[4][2];
  for (int t = 0; t < NT; ++t) {
    const int bufo  = (t & 1) << 16;
    const int nbufo = bufo ^ 65536;
    const char* LA = lds + bufo + aoff;
    const char* LB = lds + bufo + boff;

    // ---- Pa: read all B + A m0-3; stage S(t+1, A-h1) -> other buf; MFMA m0-3 x n0-1
#pragma unroll
    for (int n = 0; n < 4; ++n) {
      bF[n][0] = __builtin_bit_cast(bf16x8, *(const u16x8*)(LB + n * 2048 + ck0));
      bF[n][1] = __builtin_bit_cast(bf16x8, *(const u16x8*)(LB + n * 2048 + ck1));
    }
#pragma unroll
    for (int m = 0; m < 4; ++m) {
      aF[m][0] = __builtin_bit_cast(bf16x8, *(const u16x8*)(LA + m * 2048 + ck0));
      aF[m][1] = __builtin_bit_cast(bf16x8, *(const u16x8*)(LA + m * 2048 + ck1));
    }
    if (t + 1 < NT) STAGE(A, brow + 128, t + 1, nbufo + 16384);
    barrier_raw();
    LGKM0();
    __builtin_amdgcn_s_setprio(1);
#pragma unroll
    for (int m = 0; m < 4; ++m)
#pragma unroll
      for (int n = 0; n < 2; ++n) {
        acc[m][n] = __builtin_amdgcn_mfma_f32_16x16x32_bf16(aF[m][0], bF[n][0], acc[m][n], 0, 0, 0);
        acc[m][n] = __builtin_amdgcn_mfma_f32_16x16x32_bf16(aF[m][1], bF[n][1], acc[m][n], 0, 0, 0);
      }
    __builtin_amdgcn_s_setprio(0);
    barrier_raw();

    // ---- Pb: stage S(t+2, B-h0) (B consumed in Pa); MFMA m0-3 x n2-3
    if (t + 2 < NT) STAGE(Bt, bcol, t + 2, bufo + 32768);
    barrier_raw();
    __builtin_amdgcn_s_setprio(1);
#pragma unroll
    for (int m = 0; m < 4; ++m)
#pragma unroll
      for (int n = 2; n < 4; ++n) {
        acc[m][n] = __builtin_amdgcn_mfma_f32_16x16x32_bf16(aF[m][0], bF[n][0], acc[m][n], 0, 0, 0);
        acc[m][n] = __builtin_amdgcn_mfma_f32_16x16x32_bf16(aF[m][1], bF[n][1], acc[m][n], 0, 0, 0);
      }
    __builtin_amdgcn_s_setprio(0);
    barrier_raw();

    // ---- Pc: read A m4-7; stage S(t+2, B-h1); MFMA m4-7 x n2-3
#pragma unroll
    for (int m = 0; m < 4; ++m) {
      aF[m][0] = __builtin_bit_cast(bf16x8, *(const u16x8*)(LA + (m + 4) * 2048 + ck0));
      aF[m][1] = __builtin_bit_cast(bf16x8, *(const u16x8*)(LA + (m + 4) * 2048 + ck1));
    }
    if (t + 2 < NT) STAGE(Bt, bcol + 128, t + 2, bufo + 32768 + 16384);
    barrier_raw();
    LGKM0();
    __builtin_amdgcn_s_setprio(1);
#pragma unroll
    for (int m = 0; m < 4; ++m)
#pragma unroll
      for (int n = 2; n < 4; ++n) {
        acc[m + 4][n] = __builtin_amdgcn_mfma_f32_16x16x32_bf16(aF[m][0], bF[n][0], acc[m + 4][n], 0, 0, 0);
        acc[m + 4][n] = __builtin_amdgcn_mfma_f32_16x16x32_bf16(aF[m][1], bF[n][1], acc[m + 4][n], 0, 0, 0);
      }
    __builtin_amdgcn_s_setprio(0);
    barrier_raw();

    // ---- Pd: stage S(t+2, A-h0) (A consumed by Pc); MFMA m4-7 x n0-1; counted vmcnt
    if (t + 2 < NT) STAGE(A, brow, t + 2, bufo);
    barrier_raw();
    __builtin_amdgcn_s_setprio(1);
#pragma unroll
    for (int m = 0; m < 4; ++m)
#pragma unroll
      for (int n = 0; n < 2; ++n) {
        acc[m + 4][n] = __builtin_amdgcn_mfma_f32_16x16x32_bf16(aF[m][0], bF[n][0], acc[m + 4][n], 0, 0, 0);
        acc[m + 4][n] = __builtin_amdgcn_mfma_f32_16x16x32_bf16(aF[m][1], bF[n][1], acc[m + 4][n], 0, 0, 0);
      }
    __builtin_amdgcn_s_setprio(0);
    if (t + 2 < NT) { VMC6(); } else { VMC0(); }
    barrier_raw();
  }
}

// ---------------- GEMM1: qkv = x @ W_qkv, epilogue elu+1 on q,k; scatter (B,H,N,D) ----------------
__global__ __launch_bounds__(512, 2) void gemm_qkv(
    const unsigned short* __restrict__ xbf, const unsigned short* __restrict__ wt,
    unsigned short* __restrict__ q, unsigned short* __restrict__ k, unsigned short* __restrict__ v) {
  __shared__ __align__(16) char lds[131072];
  f32x4 acc[8][4] = {};
  const int bid = blockIdx.x;                    // 768 = 64 x 12, %8==0
  const int swz = (bid & 7) * 96 + (bid >> 3);   // bijective XCD swizzle
  const int tn = swz / 64, tm = swz % 64;
  const int brow = tm * 256, bcol = tn * 256;
  gemm256_mainloop(xbf, wt, brow, bcol, lds, acc);

  const int lane = threadIdx.x & 63, w = threadIdx.x >> 6;
  const int wr = w >> 2, wc = w & 3;
  const int lr = lane & 15, kg = lane >> 4;
#pragma unroll
  for (int m = 0; m < 8; ++m)
#pragma unroll
    for (int n = 0; n < 4; ++n)
#pragma unroll
      for (int r = 0; r < 4; ++r) {
        int grow = brow + wr * 128 + m * 16 + kg * 4 + r;
        int gcol = bcol + wc * 64 + n * 16 + lr;
        float val = acc[m][n][r];
        int tt = gcol >> 10;
        int h = (gcol >> 6) & 15;
        int d = gcol & 63;
        int b = grow >> 12, s = grow & 4095;
        size_t idx = ((size_t)(b * 16 + h) * 4096 + s) * 64 + d;
        if (tt < 2) {
          val = val > 0.f ? val + 1.f : __expf(val);  // elu(x)+1
          (tt == 0 ? q : k)[idx] = f2bf(val);
        } else {
          v[idx] = f2bf(val);
        }
      }
}

// ---------------- GEMM2: out = attn @ W_out + b ----------------
__global__ __launch_bounds__(512, 2) void gemm_out(
    const unsigned short* __restrict__ attn, const unsigned short* __restrict__ wt,
    const float* __restrict__ bias, float* __restrict__ out) {
  __shared__ __align__(16) char lds[131072];
  f32x4 acc[8][4] = {};
  const int bid = blockIdx.x;                    // 256 = 64 x 4, %8==0
  const int swz = (bid & 7) * 32 + (bid >> 3);
  const int tn = swz >> 6, tm = swz & 63;
  const int brow = tm * 256, bcol = tn * 256;
  gemm256_mainloop(attn, wt, brow, bcol, lds, acc);

  const int lane = threadIdx.x & 63, w = threadIdx.x >> 6;
  const int wr = w >> 2, wc = w & 3;
  const int lr = lane & 15, kg = lane >> 4;
#pragma unroll
  for (int m = 0; m < 8; ++m)
#pragma unroll
    for (int n = 0; n < 4; ++n)
#pragma unroll
      for (int r = 0; r < 4; ++r) {
        int grow = brow + wr * 128 + m * 16 + kg * 4 + r;
        int gcol = bcol + wc * 64 + n * 16 + lr;
        out[(size_t)grow * 1024 + gcol] = acc[m][n][r] + bias[gcol];
      }
}

// ---------------- kv[d][e] = sum_n k[n][d] v[n][e]  (stored [e][d]); ksum[d] ----------------
__global__ __launch_bounds__(256) void kv_kernel(
    const unsigned short* __restrict__ k, const unsigned short* __restrict__ v,
    float* __restrict__ kv, float* __restrict__ ksum) {
  const int bid = blockIdx.x;             // B*H*8 = 512
  const int bh = bid >> 3, chunk = bid & 7;
  const unsigned short* kb = k + (size_t)bh * 4096 * 64 + chunk * 512 * 64;
  const unsigned short* vb = v + (size_t)bh * 4096 * 64 + chunk * 512 * 64;
  __shared__ unsigned short ks[64 * 64];
  __shared__ unsigned short vs[64 * 64];
  const int tid = threadIdx.x;
  const int ty = tid >> 4, tx = tid & 15;
  float acc[4][4] = {};
  float ksacc[4] = {};
  for (int t = 0; t < 8; ++t) {
    const unsigned short* ksrc = kb + t * 4096;
    const unsigned short* vsrc = vb + t * 4096;
    *reinterpret_cast<u16x8*>(&ks[tid * 8])        = *reinterpret_cast<const u16x8*>(ksrc + tid * 8);
    *reinterpret_cast<u16x8*>(&ks[2048 + tid * 8]) = *reinterpret_cast<const u16x8*>(ksrc + 2048 + tid * 8);
    *reinterpret_cast<u16x8*>(&vs[tid * 8])        = *reinterpret_cast<const u16x8*>(vsrc + tid * 8);
    *reinterpret_cast<u16x8*>(&vs[2048 + tid * 8]) = *reinterpret_cast<const u16x8*>(vsrc + 2048 + tid * 8);
    __syncthreads();
#pragma unroll 4
    for (int nn = 0; nn < 64; ++nn) {
      u16x4 ku = *reinterpret_cast<const u16x4*>(&ks[nn * 64 + ty * 4]);
      u16x4 vu = *reinterpret_cast<const u16x4*>(&vs[nn * 64 + tx * 4]);
      float kd[4], ve[4];
#pragma unroll
      for (int i = 0; i < 4; ++i) { kd[i] = bf2f(ku[i]); ve[i] = bf2f(vu[i]); }
#pragma unroll
      for (int i = 0; i < 4; ++i) ksacc[i] += kd[i];
#pragma unroll
      for (int i = 0; i < 4; ++i)
#pragma unroll
        for (int j = 0; j < 4; ++j) acc[i][j] += kd[i] * ve[j];
    }
    __syncthreads();
  }
  float* kvb = kv + (size_t)bh * 4096;
#pragma unroll
  for (int i = 0; i < 4; ++i)
#pragma unroll
    for (int j = 0; j < 4; ++j)
      atomicAdd(&kvb[(tx * 4 + j) * 64 + ty * 4 + i], acc[i][j]);  // [e][d]
  if (tx == 0) {
#pragma unroll
    for (int i = 0; i < 4; ++i) atomicAdd(&ksum[bh * 64 + ty * 4 + i], ksacc[i]);
  }
}

// ---------------- num = q @ kv ; attn = num / (q.ksum + 1e-6) ----------------
__global__ __launch_bounds__(256) void num_kernel(
    const unsigned short* __restrict__ q, const float* __restrict__ kv,
    const float* __restrict__ ksum, unsigned short* __restrict__ attn) {
  const int bid = blockIdx.x;              // B*H*64 = 4096
  const int bh = bid >> 6, sblk = bid & 63;
  const int b = bh >> 4, h = bh & 15;
  __shared__ unsigned short kvs[64 * 72];
  __shared__ float ksum_s[64];
  __shared__ float norm_s[64];
  const int tid = threadIdx.x;
  const float* kvb = kv + (size_t)bh * 4096;
#pragma unroll
  for (int r = 0; r < 4; ++r) {
    int e = r * 1024 + tid * 4;
    float4 f = *reinterpret_cast<const float4*>(&kvb[e]);
    int row = e >> 6, col = e & 63;
    u16x4 o = { f2bf(f.x), f2bf(f.y), f2bf(f.z), f2bf(f.w) };
    *reinterpret_cast<u16x4*>(&kvs[row * 72 + col]) = o;
  }
  if (tid < 16) {
    float4 f = *reinterpret_cast<const float4*>(&ksum[bh * 64 + tid * 4]);
    ksum_s[tid * 4 + 0] = f.x; ksum_s[tid * 4 + 1] = f.y;
    ksum_s[tid * 4 + 2] = f.z; ksum_s[tid * 4 + 3] = f.w;
  }
  __syncthreads();

  const int lane = tid & 63, w = tid >> 6;
  const int lr = lane & 15, kg = lane >> 4;
  const int s0 = sblk * 64 + w * 16;
  const unsigned short* qrow = q + ((size_t)bh * 4096 + s0 + lr) * 64 + kg * 8;
  u16x8 a0u = *reinterpret_cast<const u16x8*>(qrow);
  u16x8 a1u = *reinterpret_cast<const u16x8*>(qrow + 32);
  bf16x8 a0 = __builtin_bit_cast(bf16x8, a0u);
  bf16x8 a1 = __builtin_bit_cast(bf16x8, a1u);

  float p = 0.f;
#pragma unroll
  for (int j = 0; j < 8; ++j) {
    p += bf2f(a0u[j]) * ksum_s[kg * 8 + j];
    p += bf2f(a1u[j]) * ksum_s[32 + kg * 8 + j];
  }
  p += __shfl_xor(p, 16);
  p += __shfl_xor(p, 32);
  if (kg == 0) norm_s[w * 16 + lr] = p;

  f32x4 accs[4];
#pragma unroll
  for (int jf = 0; jf < 4; ++jf) {
    u16x8 b0u = *reinterpret_cast<const u16x8*>(&kvs[(jf * 16 + lr) * 72 + kg * 8]);
    u16x8 b1u = *reinterpret_cast<const u16x8*>(&kvs[(jf * 16 + lr) * 72 + 32 + kg * 8]);
    f32x4 c = {0.f, 0.f, 0.f, 0.f};
    c = __builtin_amdgcn_mfma_f32_16x16x32_bf16(a0, __builtin_bit_cast(bf16x8, b0u), c, 0, 0, 0);
    c = __builtin_amdgcn_mfma_f32_16x16x32_bf16(a1, __builtin_bit_cast(bf16x8, b1u), c, 0, 0, 0);
    accs[jf] = c;
  }
  float dn[4];
#pragma unroll
  for (int r = 0; r < 4; ++r) dn[r] = norm_s[w * 16 + kg * 4 + r] + 1e-6f;

  unsigned short* ab = attn + (size_t)b * 4096 * 1024 + h * 64;
#pragma unroll
  for (int jf = 0; jf < 4; ++jf)
#pragma unroll
    for (int r = 0; r < 4; ++r) {
      int s = s0 + kg * 4 + r;
      int e2 = jf * 16 + lr;
      ab[(size_t)s * 1024 + e2] = f2bf(accs[jf][r] / dn[r]);
    }
}

extern "C" void kernel_launch(void* const* d_in, const int* in_sizes, int n_in,
                              void* d_out, int out_size, void* d_ws, size_t ws_size,
                              hipStream_t stream) {
  const float* x     = (const float*)d_in[0];
  const float* W_qkv = (const float*)d_in[1];
  const float* W_out = (const float*)d_in[2];
  const float* b_out = (const float*)d_in[3];
  float* out = (float*)d_out;

  unsigned short* xbf   = (unsigned short*)d_ws;            // 16384*1024
  unsigned short* attnb = xbf;                               // alias (xbf dead after gemm_qkv)
  unsigned short* wqkvT = xbf + 16777216;                    // 3072*1024
  unsigned short* woutT = wqkvT + 3145728;                   // 1024*1024
  unsigned short* qb    = woutT + 1048576;                   // 16777216
  unsigned short* kb    = qb + 16777216;
  unsigned short* vb    = kb + 16777216;
  float* kvw            = (float*)(vb + 16777216);           // 262144 f32
  float* ksumw          = kvw + 262144;                      // 4096 f32

  conv_f32_bf16<<<2048, 256, 0, stream>>>(x, xbf, 16777216);
  transpose_f32_bf16<<<dim3(48, 16), 256, 0, stream>>>(W_qkv, wqkvT, 1024, 3072);
  transpose_f32_bf16<<<dim3(16, 16), 256, 0, stream>>>(W_out, woutT, 1024, 1024);
  hipMemsetAsync(kvw, 0, (262144 + 4096) * sizeof(float), stream);
  gemm_qkv<<<768, 512, 0, stream>>>(xbf, wqkvT, qb, kb, vb);
  kv_kernel<<<512, 256, 0, stream>>>(kb, vb, kvw, ksumw);
  num_kernel<<<4096, 256, 0, stream>>>(qb, kvw, ksumw, attnb);
  gemm_out<<<256, 512, 0, stream>>>(attnb, woutT, b_out, out);
}

// Round 5
// 261.192 us; speedup vs baseline: 1.2294x; 1.0290x over previous
//
#include <hip/hip_runtime.h>
#include <hip/hip_bf16.h>

using bf16x8 = __bf16 __attribute__((ext_vector_type(8)));
using f32x4  = float  __attribute__((ext_vector_type(4)));
using u16x8  = unsigned short __attribute__((ext_vector_type(8)));
using u16x4  = unsigned short __attribute__((ext_vector_type(4)));

__device__ __forceinline__ unsigned short f2bf(float f) {
  unsigned u = __builtin_bit_cast(unsigned, f);
  u += 0x7fffu + ((u >> 16) & 1u);
  return (unsigned short)(u >> 16);
}
__device__ __forceinline__ float bf2f(unsigned short h) {
  return __builtin_bit_cast(float, (unsigned)h << 16);
}

__device__ __forceinline__ void gload16(const void* g, void* l) {
  __builtin_amdgcn_global_load_lds(
      (const __attribute__((address_space(1))) void*)g,
      (__attribute__((address_space(3))) void*)l, 16, 0, 0);
}

__device__ __forceinline__ void barrier_raw() {
  asm volatile("" ::: "memory");
  __builtin_amdgcn_s_barrier();
  asm volatile("" ::: "memory");
}
#define LGKM0() asm volatile("s_waitcnt lgkmcnt(0)" ::: "memory")
#define VMC6()  asm volatile("s_waitcnt vmcnt(6)" ::: "memory")
#define VMC0()  asm volatile("s_waitcnt vmcnt(0)" ::: "memory")

// ---------------- convert f32 -> bf16 (vectorized) ----------------
__global__ __launch_bounds__(256) void conv_f32_bf16(const float* __restrict__ in,
                                                     unsigned short* __restrict__ out, int n) {
  int stride = gridDim.x * 256 * 4;
  for (int i = (blockIdx.x * 256 + threadIdx.x) * 4; i < n; i += stride) {
    float4 v = *reinterpret_cast<const float4*>(in + i);
    u16x4 o = { f2bf(v.x), f2bf(v.y), f2bf(v.z), f2bf(v.w) };
    *reinterpret_cast<u16x4*>(out + i) = o;
  }
}

// ---------------- transpose + convert: out[c][r] = bf16(in[r][c]) ----------------
__global__ __launch_bounds__(256) void transpose_f32_bf16(const float* __restrict__ in,
                                                          unsigned short* __restrict__ out,
                                                          int R, int C) {
  __shared__ float t[64][65];
  int c0 = blockIdx.x * 64, r0 = blockIdx.y * 64;
  int lx = threadIdx.x & 63, ly = threadIdx.x >> 6;
#pragma unroll
  for (int i = 0; i < 16; ++i) {
    int r = ly * 16 + i;
    t[r][lx] = in[(size_t)(r0 + r) * C + c0 + lx];
  }
  __syncthreads();
#pragma unroll
  for (int i = 0; i < 16; ++i) {
    int c = ly * 16 + i;
    out[(size_t)(c0 + c) * R + r0 + lx] = f2bf(t[lx][c]);
  }
}

// ================= 256x256, BK=64, 8-wave, 8-phase GEMM mainloop =================
// LDS per buffer (64KB): A [2 halves][128][64]bf16 at +0, B same at +32768.
// Double buffer -> 128KB. Reads XOR-swizzled (byte ^= (row&7)<<4); stages use
// linear LDS dest + inverse-swizzled global source (involution).
// Phase balance: Pa reads A m0-3 + B n0-1 (12), Pb reads B n2-3 (4),
// Pc reads A m4-7 (8), Pd reads 0. Stages: Pa->A-h1(t+1,nbuf), Pc->B-h0(t+2),
// Pd->B-h1(t+2)+A-h0(t+2). Overwrite safety: B reads end at Pb (lgkm+barrier),
// A reads end at Pc; all stages of a region issue >=1 barrier after last read.
__device__ __forceinline__ void gemm256_mainloop(
    const unsigned short* __restrict__ A, const unsigned short* __restrict__ Bt,
    int brow, int bcol, char* lds, f32x4 (&acc)[8][4]) {
  constexpr int NT = 16;  // K = 1024 / 64
  const int tid  = threadIdx.x;
  const int lane = tid & 63;
  const int w    = tid >> 6;
  const int wr   = w >> 2, wc = w & 3;
  const int lr   = lane & 15, kg = lane >> 4;

  const int o0 = tid * 16;
  const int o1 = 8192 + tid * 16;
  const int p0 = o0 ^ (((o0 >> 7) & 7) << 4);
  const int p1 = o1 ^ (((o1 >> 7) & 7) << 4);
  const int off0 = (p0 >> 7) * 2048 + (p0 & 127);
  const int off1 = (p1 >> 7) * 2048 + (p1 & 127);
  const int wq = w << 10;

  const int xr  = (lr & 7) << 4;
  const int ck0 = (kg * 16) ^ xr;
  const int ck1 = (64 + kg * 16) ^ xr;
  const int aoff = wr * 16384 + lr * 128;
  const int boff = 32768 + (wc >> 1) * 16384 + (wc & 1) * 8192 + lr * 128;

  auto STAGE = [&](const unsigned short* G, int rowbase, int t, int region) {
    const char* gb = (const char*)(G + (size_t)rowbase * 1024 + t * 64);
    char* lb = lds + region + wq;
    gload16(gb + off0, lb);
    gload16(gb + off1, lb + 8192);
  };

  // ---- prologue: tile0 full + 3 half-tiles of tile1 ----
  STAGE(Bt, bcol,       0, 32768);
  STAGE(Bt, bcol + 128, 0, 32768 + 16384);
  STAGE(A,  brow,       0, 0);
  STAGE(A,  brow + 128, 0, 16384);
  STAGE(Bt, bcol,       1, 65536 + 32768);
  STAGE(Bt, bcol + 128, 1, 65536 + 32768 + 16384);
  STAGE(A,  brow,       1, 65536);
  VMC6();
  barrier_raw();

  bf16x8 aF[4][2], bF[4][2];
  for (int t = 0; t < NT; ++t) {
    const int bufo  = (t & 1) << 16;
    const int nbufo = bufo ^ 65536;
    const char* LA = lds + bufo + aoff;
    const char* LB = lds + bufo + boff;

    // ---- Pa: read A m0-3 + B n0-1; stage A-h1(t+1)->nbuf; MFMA m0-3 x n0-1
#pragma unroll
    for (int n = 0; n < 2; ++n) {
      bF[n][0] = __builtin_bit_cast(bf16x8, *(const u16x8*)(LB + n * 2048 + ck0));
      bF[n][1] = __builtin_bit_cast(bf16x8, *(const u16x8*)(LB + n * 2048 + ck1));
    }
#pragma unroll
    for (int m = 0; m < 4; ++m) {
      aF[m][0] = __builtin_bit_cast(bf16x8, *(const u16x8*)(LA + m * 2048 + ck0));
      aF[m][1] = __builtin_bit_cast(bf16x8, *(const u16x8*)(LA + m * 2048 + ck1));
    }
    if (t + 1 < NT) STAGE(A, brow + 128, t + 1, nbufo + 16384);
    barrier_raw();
    LGKM0();
    __builtin_amdgcn_s_setprio(1);
#pragma unroll
    for (int kk = 0; kk < 2; ++kk)
#pragma unroll
      for (int m = 0; m < 4; ++m)
#pragma unroll
        for (int n = 0; n < 2; ++n)
          acc[m][n] = __builtin_amdgcn_mfma_f32_16x16x32_bf16(aF[m][kk], bF[n][kk], acc[m][n], 0, 0, 0);
    __builtin_amdgcn_s_setprio(0);
    barrier_raw();

    // ---- Pb: read B n2-3; MFMA m0-3 x n2-3
#pragma unroll
    for (int n = 2; n < 4; ++n) {
      bF[n][0] = __builtin_bit_cast(bf16x8, *(const u16x8*)(LB + n * 2048 + ck0));
      bF[n][1] = __builtin_bit_cast(bf16x8, *(const u16x8*)(LB + n * 2048 + ck1));
    }
    barrier_raw();
    LGKM0();
    __builtin_amdgcn_s_setprio(1);
#pragma unroll
    for (int kk = 0; kk < 2; ++kk)
#pragma unroll
      for (int m = 0; m < 4; ++m)
#pragma unroll
        for (int n = 2; n < 4; ++n)
          acc[m][n] = __builtin_amdgcn_mfma_f32_16x16x32_bf16(aF[m][kk], bF[n][kk], acc[m][n], 0, 0, 0);
    __builtin_amdgcn_s_setprio(0);
    barrier_raw();

    // ---- Pc: read A m4-7; stage B-h0(t+2); MFMA m4-7 x n2-3
#pragma unroll
    for (int m = 0; m < 4; ++m) {
      aF[m][0] = __builtin_bit_cast(bf16x8, *(const u16x8*)(LA + (m + 4) * 2048 + ck0));
      aF[m][1] = __builtin_bit_cast(bf16x8, *(const u16x8*)(LA + (m + 4) * 2048 + ck1));
    }
    if (t + 2 < NT) STAGE(Bt, bcol, t + 2, bufo + 32768);
    barrier_raw();
    LGKM0();
    __builtin_amdgcn_s_setprio(1);
#pragma unroll
    for (int kk = 0; kk < 2; ++kk)
#pragma unroll
      for (int m = 0; m < 4; ++m)
#pragma unroll
        for (int n = 2; n < 4; ++n)
          acc[m + 4][n] = __builtin_amdgcn_mfma_f32_16x16x32_bf16(aF[m][kk], bF[n][kk], acc[m + 4][n], 0, 0, 0);
    __builtin_amdgcn_s_setprio(0);
    barrier_raw();

    // ---- Pd: stage B-h1(t+2) + A-h0(t+2); MFMA m4-7 x n0-1; counted vmcnt
    if (t + 2 < NT) {
      STAGE(Bt, bcol + 128, t + 2, bufo + 32768 + 16384);
      STAGE(A,  brow,       t + 2, bufo);
    }
    barrier_raw();
    __builtin_amdgcn_s_setprio(1);
#pragma unroll
    for (int kk = 0; kk < 2; ++kk)
#pragma unroll
      for (int m = 0; m < 4; ++m)
#pragma unroll
        for (int n = 0; n < 2; ++n)
          acc[m + 4][n] = __builtin_amdgcn_mfma_f32_16x16x32_bf16(aF[m][kk], bF[n][kk], acc[m + 4][n], 0, 0, 0);
    __builtin_amdgcn_s_setprio(0);
    if (t + 2 < NT) { VMC6(); } else { VMC0(); }
    barrier_raw();
  }
}

// ---------------- GEMM1: qkv = x @ W_qkv, epilogue elu+1 on q,k; scatter (B,H,N,D) ----------------
__global__ __launch_bounds__(512, 2) void gemm_qkv(
    const unsigned short* __restrict__ xbf, const unsigned short* __restrict__ wt,
    unsigned short* __restrict__ q, unsigned short* __restrict__ k, unsigned short* __restrict__ v) {
  __shared__ __align__(16) char lds[131072];
  f32x4 acc[8][4] = {};
  // L2-patch grid: XCD r owns tm stripe [8r,8r+8), tn-major within the stripe.
  // Concurrent per-XCD working set: 8 A-panels (4MB, L2-resident, 12x reuse) + streaming B.
  const int bid = blockIdx.x;                    // 768 = 8 XCD x 8 tm x 12 tn
  const int r = bid & 7, i = bid >> 3;
  const int tm = r * 8 + (i & 7);
  const int tn = i >> 3;
  const int brow = tm * 256, bcol = tn * 256;
  gemm256_mainloop(xbf, wt, brow, bcol, lds, acc);

  const int lane = threadIdx.x & 63, w = threadIdx.x >> 6;
  const int wr = w >> 2, wc = w & 3;
  const int lr = lane & 15, kg = lane >> 4;
#pragma unroll
  for (int m = 0; m < 8; ++m)
#pragma unroll
    for (int n = 0; n < 4; ++n)
#pragma unroll
      for (int rr = 0; rr < 4; ++rr) {
        int grow = brow + wr * 128 + m * 16 + kg * 4 + rr;
        int gcol = bcol + wc * 64 + n * 16 + lr;
        float val = acc[m][n][rr];
        int tt = gcol >> 10;
        int h = (gcol >> 6) & 15;
        int d = gcol & 63;
        int b = grow >> 12, s = grow & 4095;
        size_t idx = ((size_t)(b * 16 + h) * 4096 + s) * 64 + d;
        if (tt < 2) {
          val = val > 0.f ? val + 1.f : __expf(val);  // elu(x)+1
          (tt == 0 ? q : k)[idx] = f2bf(val);
        } else {
          v[idx] = f2bf(val);
        }
      }
}

// ---------------- GEMM2: out = attn @ W_out + b ----------------
__global__ __launch_bounds__(512, 2) void gemm_out(
    const unsigned short* __restrict__ attn, const unsigned short* __restrict__ wt,
    const float* __restrict__ bias, float* __restrict__ out) {
  __shared__ __align__(16) char lds[131072];
  f32x4 acc[8][4] = {};
  const int bid = blockIdx.x;                    // 256 = 8 XCD x 8 tm x 4 tn
  const int r = bid & 7, i = bid >> 3;
  const int tm = r * 8 + (i & 7);
  const int tn = i >> 3;
  const int brow = tm * 256, bcol = tn * 256;
  gemm256_mainloop(attn, wt, brow, bcol, lds, acc);

  const int lane = threadIdx.x & 63, w = threadIdx.x >> 6;
  const int wr = w >> 2, wc = w & 3;
  const int lr = lane & 15, kg = lane >> 4;
#pragma unroll
  for (int m = 0; m < 8; ++m)
#pragma unroll
    for (int n = 0; n < 4; ++n)
#pragma unroll
      for (int rr = 0; rr < 4; ++rr) {
        int grow = brow + wr * 128 + m * 16 + kg * 4 + rr;
        int gcol = bcol + wc * 64 + n * 16 + lr;
        out[(size_t)grow * 1024 + gcol] = acc[m][n][rr] + bias[gcol];
      }
}

// ---------------- kv[d][e] = sum_n k[n][d] v[n][e]  (stored [e][d]); ksum[d] ----------------
__global__ __launch_bounds__(256) void kv_kernel(
    const unsigned short* __restrict__ k, const unsigned short* __restrict__ v,
    float* __restrict__ kv, float* __restrict__ ksum) {
  const int bid = blockIdx.x;             // B*H*8 = 512
  const int bh = bid >> 3, chunk = bid & 7;
  const unsigned short* kb = k + (size_t)bh * 4096 * 64 + chunk * 512 * 64;
  const unsigned short* vb = v + (size_t)bh * 4096 * 64 + chunk * 512 * 64;
  __shared__ unsigned short ks[64 * 64];
  __shared__ unsigned short vs[64 * 64];
  const int tid = threadIdx.x;
  const int ty = tid >> 4, tx = tid & 15;
  float acc[4][4] = {};
  float ksacc[4] = {};
  for (int t = 0; t < 8; ++t) {
    const unsigned short* ksrc = kb + t * 4096;
    const unsigned short* vsrc = vb + t * 4096;
    *reinterpret_cast<u16x8*>(&ks[tid * 8])        = *reinterpret_cast<const u16x8*>(ksrc + tid * 8);
    *reinterpret_cast<u16x8*>(&ks[2048 + tid * 8]) = *reinterpret_cast<const u16x8*>(ksrc + 2048 + tid * 8);
    *reinterpret_cast<u16x8*>(&vs[tid * 8])        = *reinterpret_cast<const u16x8*>(vsrc + tid * 8);
    *reinterpret_cast<u16x8*>(&vs[2048 + tid * 8]) = *reinterpret_cast<const u16x8*>(vsrc + 2048 + tid * 8);
    __syncthreads();
#pragma unroll 4
    for (int nn = 0; nn < 64; ++nn) {
      u16x4 ku = *reinterpret_cast<const u16x4*>(&ks[nn * 64 + ty * 4]);
      u16x4 vu = *reinterpret_cast<const u16x4*>(&vs[nn * 64 + tx * 4]);
      float kd[4], ve[4];
#pragma unroll
      for (int i = 0; i < 4; ++i) { kd[i] = bf2f(ku[i]); ve[i] = bf2f(vu[i]); }
#pragma unroll
      for (int i = 0; i < 4; ++i) ksacc[i] += kd[i];
#pragma unroll
      for (int i = 0; i < 4; ++i)
#pragma unroll
        for (int j = 0; j < 4; ++j) acc[i][j] += kd[i] * ve[j];
    }
    __syncthreads();
  }
  float* kvb = kv + (size_t)bh * 4096;
#pragma unroll
  for (int i = 0; i < 4; ++i)
#pragma unroll
    for (int j = 0; j < 4; ++j)
      atomicAdd(&kvb[(tx * 4 + j) * 64 + ty * 4 + i], acc[i][j]);  // [e][d]
  if (tx == 0) {
#pragma unroll
    for (int i = 0; i < 4; ++i) atomicAdd(&ksum[bh * 64 + ty * 4 + i], ksacc[i]);
  }
}

// ---------------- num = q @ kv ; attn = num / (q.ksum + 1e-6) ----------------
__global__ __launch_bounds__(256) void num_kernel(
    const unsigned short* __restrict__ q, const float* __restrict__ kv,
    const float* __restrict__ ksum, unsigned short* __restrict__ attn) {
  const int bid = blockIdx.x;              // B*H*64 = 4096
  const int bh = bid >> 6, sblk = bid & 63;
  const int b = bh >> 4, h = bh & 15;
  __shared__ unsigned short kvs[64 * 72];
  __shared__ float ksum_s[64];
  __shared__ float norm_s[64];
  const int tid = threadIdx.x;
  const float* kvb = kv + (size_t)bh * 4096;
#pragma unroll
  for (int r = 0; r < 4; ++r) {
    int e = r * 1024 + tid * 4;
    float4 f = *reinterpret_cast<const float4*>(&kvb[e]);
    int row = e >> 6, col = e & 63;
    u16x4 o = { f2bf(f.x), f2bf(f.y), f2bf(f.z), f2bf(f.w) };
    *reinterpret_cast<u16x4*>(&kvs[row * 72 + col]) = o;
  }
  if (tid < 16) {
    float4 f = *reinterpret_cast<const float4*>(&ksum[bh * 64 + tid * 4]);
    ksum_s[tid * 4 + 0] = f.x; ksum_s[tid * 4 + 1] = f.y;
    ksum_s[tid * 4 + 2] = f.z; ksum_s[tid * 4 + 3] = f.w;
  }
  __syncthreads();

  const int lane = tid & 63, w = tid >> 6;
  const int lr = lane & 15, kg = lane >> 4;
  const int s0 = sblk * 64 + w * 16;
  const unsigned short* qrow = q + ((size_t)bh * 4096 + s0 + lr) * 64 + kg * 8;
  u16x8 a0u = *reinterpret_cast<const u16x8*>(qrow);
  u16x8 a1u = *reinterpret_cast<const u16x8*>(qrow + 32);
  bf16x8 a0 = __builtin_bit_cast(bf16x8, a0u);
  bf16x8 a1 = __builtin_bit_cast(bf16x8, a1u);

  float p = 0.f;
#pragma unroll
  for (int j = 0; j < 8; ++j) {
    p += bf2f(a0u[j]) * ksum_s[kg * 8 + j];
    p += bf2f(a1u[j]) * ksum_s[32 + kg * 8 + j];
  }
  p += __shfl_xor(p, 16);
  p += __shfl_xor(p, 32);
  if (kg == 0) norm_s[w * 16 + lr] = p;

  f32x4 accs[4];
#pragma unroll
  for (int jf = 0; jf < 4; ++jf) {
    u16x8 b0u = *reinterpret_cast<const u16x8*>(&kvs[(jf * 16 + lr) * 72 + kg * 8]);
    u16x8 b1u = *reinterpret_cast<const u16x8*>(&kvs[(jf * 16 + lr) * 72 + 32 + kg * 8]);
    f32x4 c = {0.f, 0.f, 0.f, 0.f};
    c = __builtin_amdgcn_mfma_f32_16x16x32_bf16(a0, __builtin_bit_cast(bf16x8, b0u), c, 0, 0, 0);
    c = __builtin_amdgcn_mfma_f32_16x16x32_bf16(a1, __builtin_bit_cast(bf16x8, b1u), c, 0, 0, 0);
    accs[jf] = c;
  }
  float dn[4];
#pragma unroll
  for (int r = 0; r < 4; ++r) dn[r] = norm_s[w * 16 + kg * 4 + r] + 1e-6f;

  unsigned short* ab = attn + (size_t)b * 4096 * 1024 + h * 64;
#pragma unroll
  for (int jf = 0; jf < 4; ++jf)
#pragma unroll
    for (int r = 0; r < 4; ++r) {
      int s = s0 + kg * 4 + r;
      int e2 = jf * 16 + lr;
      ab[(size_t)s * 1024 + e2] = f2bf(accs[jf][r] / dn[r]);
    }
}

extern "C" void kernel_launch(void* const* d_in, const int* in_sizes, int n_in,
                              void* d_out, int out_size, void* d_ws, size_t ws_size,
                              hipStream_t stream) {
  const float* x     = (const float*)d_in[0];
  const float* W_qkv = (const float*)d_in[1];
  const float* W_out = (const float*)d_in[2];
  const float* b_out = (const float*)d_in[3];
  float* out = (float*)d_out;

  unsigned short* xbf   = (unsigned short*)d_ws;            // 16384*1024
  unsigned short* attnb = xbf;                               // alias (xbf dead after gemm_qkv)
  unsigned short* wqkvT = xbf + 16777216;                    // 3072*1024
  unsigned short* woutT = wqkvT + 3145728;                   // 1024*1024
  unsigned short* qb    = woutT + 1048576;                   // 16777216
  unsigned short* kb    = qb + 16777216;
  unsigned short* vb    = kb + 16777216;
  float* kvw            = (float*)(vb + 16777216);           // 262144 f32
  float* ksumw          = kvw + 262144;                      // 4096 f32

  conv_f32_bf16<<<2048, 256, 0, stream>>>(x, xbf, 16777216);
  transpose_f32_bf16<<<dim3(48, 16), 256, 0, stream>>>(W_qkv, wqkvT, 1024, 3072);
  transpose_f32_bf16<<<dim3(16, 16), 256, 0, stream>>>(W_out, woutT, 1024, 1024);
  hipMemsetAsync(kvw, 0, (262144 + 4096) * sizeof(float), stream);
  gemm_qkv<<<768, 512, 0, stream>>>(xbf, wqkvT, qb, kb, vb);
  kv_kernel<<<512, 256, 0, stream>>>(kb, vb, kvw, ksumw);
  num_kernel<<<4096, 256, 0, stream>>>(qb, kvw, ksumw, attnb);
  gemm_out<<<256, 512, 0, stream>>>(attnb, woutT, b_out, out);
}